// Round 3
// baseline (616.066 us; speedup 1.0000x reference)
//
#include <hip/hip_runtime.h>
#include <math.h>

// GraphConvolution (GCNII variant=True, residual=True), N=100k, E=1M, D=64.
//   agg[dst] += h[src] * edge_w    (bucket-binned, LDS-privatized SpMM)
//   out = theta*([agg,i]@W) + (1-theta)*((1-alpha)*agg + alpha*i) + i
//
// R3: CSR build (hist/scan/apply/fill, ~90us, 8x write-amplified scatter)
// replaced by single-pass LDS-binned bucket fill + per-bucket LDS-accumulated
// SpMM. agg lives in d_out (epilogue is in-place per-row) -> ws ~12.8 MB.

#define DFEAT 64
#define NBINS 512        // physical arrays; logical bins = (N+255)>>8 = 391
#define CAP   4096       // entries per bucket (mean 2558, sigma ~51 -> safe)
#define CHUNK 4096       // edges per bin_fill block

__device__ inline float lane_bcast(float v, int l) {
    return __uint_as_float(__builtin_amdgcn_readlane(__float_as_uint(v), l));
}

// ---- phase 1: bin edges by dst>>8 into fixed-capacity global buckets ----
// Entry: low32 = src | (dstLocal<<24), high32 = bits(w). src < 2^17, dl < 256.
__global__ __launch_bounds__(256) void bin_fill_kernel(
    const int* __restrict__ e_src, const int* __restrict__ e_dst,
    const float* __restrict__ e_w, int* __restrict__ gcur,
    unsigned long long* __restrict__ bucket, int E) {
    __shared__ unsigned long long staging[CHUNK];   // 32 KB
    __shared__ unsigned short binOf[CHUNK];         // 8 KB
    __shared__ int hist[NBINS], offs[NBINS], cur[NBINS], gbase[NBINS];
    __shared__ int part[256];

    int tid = threadIdx.x;
    int e0 = blockIdx.x * CHUNK;
    int cc = min(CHUNK, E - e0);

    hist[tid] = 0; hist[tid + 256] = 0;
    __syncthreads();

    // count
    for (int it = 0; it < CHUNK / 256; ++it) {
        int e = e0 + it * 256 + tid;
        if (e < E) atomicAdd(&hist[e_dst[e] >> 8], 1);
    }
    __syncthreads();

    // exclusive scan of hist[512]: thread t owns pair (2t, 2t+1)
    int a = hist[2 * tid], b = hist[2 * tid + 1];
    part[tid] = a + b;
    __syncthreads();
    for (int ofs = 1; ofs < 256; ofs <<= 1) {
        int v = (tid >= ofs) ? part[tid - ofs] : 0;
        __syncthreads();
        part[tid] += v;
        __syncthreads();
    }
    int excl = part[tid] - (a + b);
    offs[2 * tid] = excl;       cur[2 * tid] = excl;
    offs[2 * tid + 1] = excl + a; cur[2 * tid + 1] = excl + a;
    __syncthreads();

    // scatter into bin-sorted LDS staging
    for (int it = 0; it < CHUNK / 256; ++it) {
        int e = e0 + it * 256 + tid;
        if (e < E) {
            int d = e_dst[e];
            int bb = d >> 8;
            int p = atomicAdd(&cur[bb], 1);
            unsigned lo = (unsigned)e_src[e] | ((unsigned)(d & 255) << 24);
            staging[p] = ((unsigned long long)(unsigned)__float_as_int(e_w[e]) << 32) | lo;
            binOf[p] = (unsigned short)bb;
        }
    }
    __syncthreads();

    // reserve global space: one atomic per non-empty bin
    for (int t = tid; t < NBINS; t += 256) {
        int c = hist[t];
        gbase[t] = (c > 0) ? atomicAdd(&gcur[t], c) : 0;
    }
    __syncthreads();

    // flush: consecutive staged slots in a bin -> consecutive global slots
    for (int it = 0; it < CHUNK / 256; ++it) {
        int p = it * 256 + tid;
        if (p < cc) {
            int bb = binOf[p];
            int idx = gbase[bb] + (p - offs[bb]);
            bucket[(size_t)bb * CAP + idx] = staging[p];
        }
    }
}

// ---- phase 2: per-bucket SpMM with LDS-privatized accumulator ----
__global__ __launch_bounds__(512) void bucket_spmm_kernel(
    const float* __restrict__ h, const unsigned long long* __restrict__ bucket,
    const int* __restrict__ gcur, float* __restrict__ agg, int N) {
    __shared__ float acc[256 * DFEAT];   // 64 KB
    int tid = threadIdx.x;
    int bin = blockIdx.x;
    int base = bin << 8;

    for (int i = tid; i < 256 * DFEAT; i += 512) acc[i] = 0.f;
    int cnt = gcur[bin];
    __syncthreads();

    int lane = tid & 63, wv = tid >> 6;   // 8 waves
    const unsigned long long* bk = bucket + (size_t)bin * CAP;

    for (int t0 = wv * 8; t0 < cnt; t0 += 64) {
        int m = cnt - t0;
        float v[8], w[8];
        int dl[8];
#pragma unroll
        for (int j = 0; j < 8; ++j) {
            if (j < m) {
                unsigned long long e = bk[t0 + j];
                unsigned lo = (unsigned)e;
                int src = lo & 0xFFFFFF;
                dl[j] = lo >> 24;
                w[j] = __int_as_float((int)(e >> 32));
                v[j] = h[(size_t)src * DFEAT + lane];
            }
        }
#pragma unroll
        for (int j = 0; j < 8; ++j) {
            if (j < m) atomicAdd(&acc[dl[j] * DFEAT + lane], w[j] * v[j]);
        }
    }
    __syncthreads();

    int nn = min(256, N - base);
    for (int r = wv; r < nn; r += 8)
        agg[(size_t)(base + r) * DFEAT + lane] = acc[r * DFEAT + lane];
}

// ---- epilogue: register-resident W, readlane broadcast (in-place on agg) ----
__global__ __launch_bounds__(256) void epilogue_kernel(
    const float* __restrict__ agg, const float* __restrict__ ifeat,
    const float* __restrict__ weight,   // [128][64] row-major
    const float* __restrict__ lamda_p, const float* __restrict__ alpha_p,
    const int* __restrict__ layer_p,
    float* __restrict__ out, int N, int total_waves) {
    int lane = threadIdx.x & 63;
    int wave = (blockIdx.x * 256 + threadIdx.x) >> 6;

    float wreg[128];
#pragma unroll
    for (int k = 0; k < 128; ++k) wreg[k] = weight[k * DFEAT + lane];

    float lam = lamda_p[0];
    float alpha = alpha_p[0];
    float theta = fminf(1.0f, logf(lam / (float)layer_p[0] + 1.0f));

    for (int r = wave; r < N; r += total_waves) {
        float hv = agg[(size_t)r * DFEAT + lane];
        float iv = ifeat[(size_t)r * DFEAT + lane];
        float acc = 0.f;
#pragma unroll
        for (int k = 0; k < 64; ++k)
            acc += lane_bcast(hv, k) * wreg[k];
#pragma unroll
        for (int k = 0; k < 64; ++k)
            acc += lane_bcast(iv, k) * wreg[64 + k];
        out[(size_t)r * DFEAT + lane] =
            theta * acc + (1.f - theta) * ((1.f - alpha) * hv + alpha * iv) + iv;
    }
}

extern "C" void kernel_launch(void* const* d_in, const int* in_sizes, int n_in,
                              void* d_out, int out_size, void* d_ws, size_t ws_size,
                              hipStream_t stream) {
    const float* h       = (const float*)d_in[0];
    const float* ifeat   = (const float*)d_in[1];
    const float* weight  = (const float*)d_in[2];
    const float* edge_w  = (const float*)d_in[3];
    const float* lamda_p = (const float*)d_in[4];
    const float* alpha_p = (const float*)d_in[5];
    const int*   e_src   = (const int*)d_in[6];
    const int*   e_dst   = (const int*)d_in[7];
    const int*   layer_p = (const int*)d_in[8];
    float* out = (float*)d_out;

    int N = in_sizes[0] / DFEAT;     // 100000
    int E = in_sizes[3];             // 1000000
    int nbins = (N + 255) >> 8;      // 391

    // ws layout: gcur[NBINS] ints, then bucket[nbins*CAP] u64 (~12.8 MB)
    int* gcur = (int*)d_ws;
    unsigned long long* bucket =
        (unsigned long long*)((char*)d_ws + NBINS * sizeof(int) + 2048);

    // agg lives in d_out (epilogue is in-place per-row)
    float* agg = out;

    hipMemsetAsync(gcur, 0, NBINS * sizeof(int), stream);

    bin_fill_kernel<<<(E + CHUNK - 1) / CHUNK, 256, 0, stream>>>(
        e_src, e_dst, edge_w, gcur, bucket, E);

    bucket_spmm_kernel<<<nbins, 512, 0, stream>>>(h, bucket, gcur, agg, N);

    int epi_blocks = 768;
    epilogue_kernel<<<epi_blocks, 256, 0, stream>>>(
        agg, ifeat, weight, lamda_p, alpha_p, layer_p, out, N, epi_blocks * 4);
}

// Round 4
// 233.316 us; speedup vs baseline: 2.6405x; 2.6405x over previous
//
#include <hip/hip_runtime.h>
#include <math.h>

// GraphConvolution (GCNII variant=True, residual=True), N=100k, E=1M, D=64.
//   agg[dst] += h[src] * edge_w
//   out = theta*([agg,i]@W) + (1-theta)*((1-alpha)*agg + alpha*i) + i
//
// R4: producer = bin_fill (bin-sorted buckets, coalesced-ish runs) +
// local_sort (per-bin counting sort -> exact per-node CSR, coalesced).
// Consumer = R2's proven wave-per-node gather (high occupancy / MLP).
// R3's LDS-privatized bucket_spmm (446us, latency-starved) is dropped.

#define DFEAT 64
#define NBINS 512        // physical; logical bins = ceil(N/256) = 391
#define CAP   4096       // slots per bucket (mean 2558, sigma ~51)
#define CHUNK 4096       // edges per bin_fill block
#define TPB   512

typedef unsigned long long u64;

__device__ inline float lane_bcast(float v, int l) {
    return __uint_as_float(__builtin_amdgcn_readlane(__float_as_uint(v), l));
}

// ---- phase 1: bin edges by dst>>8 into fixed-capacity global buckets ----
// Entry: low32 = src | (dstLocal<<24), high32 = bits(w).
__global__ __launch_bounds__(512) void bin_fill_kernel(
    const int* __restrict__ e_src, const int* __restrict__ e_dst,
    const float* __restrict__ e_w, int* __restrict__ gcur,
    u64* __restrict__ bucket, int E) {
    __shared__ u64 staging[CHUNK];            // 32 KB
    __shared__ unsigned short binOf[CHUNK];   // 8 KB
    __shared__ int hist[NBINS], offs[NBINS], gbase[NBINS];
    __shared__ int cur[NBINS], part[TPB];

    int tid = threadIdx.x;
    int e0 = blockIdx.x * CHUNK;
    int cc = min(CHUNK, E - e0);

    hist[tid] = 0;
    __syncthreads();

    // load edges into registers (coalesced, pipelined) + count
    int d[8], s[8];
    float w[8];
#pragma unroll
    for (int j = 0; j < 8; ++j) {
        int e = e0 + j * TPB + tid;
        if (e < E) {
            d[j] = e_dst[e]; s[j] = e_src[e]; w[j] = e_w[e];
        } else d[j] = -1;
    }
#pragma unroll
    for (int j = 0; j < 8; ++j)
        if (d[j] >= 0) atomicAdd(&hist[d[j] >> 8], 1);
    __syncthreads();

    // exclusive scan of hist[512]
    int v = hist[tid];
    part[tid] = v;
    __syncthreads();
    for (int ofs = 1; ofs < TPB; ofs <<= 1) {
        int t = (tid >= ofs) ? part[tid - ofs] : 0;
        __syncthreads();
        part[tid] += t;
        __syncthreads();
    }
    int excl = part[tid] - v;
    offs[tid] = excl; cur[tid] = excl;
    __syncthreads();

    // scatter into bin-sorted LDS staging
#pragma unroll
    for (int j = 0; j < 8; ++j) {
        if (d[j] >= 0) {
            int bb = d[j] >> 8;
            int p = atomicAdd(&cur[bb], 1);
            unsigned lo = (unsigned)s[j] | ((unsigned)(d[j] & 255) << 24);
            staging[p] = ((u64)(unsigned)__float_as_int(w[j]) << 32) | lo;
            binOf[p] = (unsigned short)bb;
        }
    }
    __syncthreads();

    // reserve global space: one atomic per non-empty bin
    {
        int c = hist[tid];
        gbase[tid] = (c > 0) ? atomicAdd(&gcur[tid], c) : 0;
    }
    __syncthreads();

    // flush: bin-contiguous runs -> contiguous global slots
#pragma unroll
    for (int j = 0; j < 8; ++j) {
        int p = j * TPB + tid;
        if (p < cc) {
            int bb = binOf[p];
            bucket[(size_t)bb * CAP + gbase[bb] + (p - offs[bb])] = staging[p];
        }
    }
}

// ---- phase 2: per-bin counting sort by node -> exact CSR (in place) ----
__global__ __launch_bounds__(256) void local_sort_kernel(
    u64* __restrict__ bucket, const int* __restrict__ gcur,
    int* __restrict__ rstart, int* __restrict__ rdeg, int N) {
    __shared__ u64 stag[CAP];      // 32 KB
    __shared__ u64 sorted[CAP];    // 32 KB
    __shared__ int hist[256], start[256], cur[256], part[256];

    int bin = blockIdx.x, tid = threadIdx.x;
    int cnt = gcur[bin];
    u64* bk = bucket + (size_t)bin * CAP;

    hist[tid] = 0;
    __syncthreads();

    for (int p = tid; p < cnt; p += 256) {
        u64 e = bk[p];
        stag[p] = e;
        atomicAdd(&hist[((unsigned)e) >> 24], 1);
    }
    __syncthreads();

    int v = hist[tid];
    part[tid] = v;
    __syncthreads();
    for (int ofs = 1; ofs < 256; ofs <<= 1) {
        int t = (tid >= ofs) ? part[tid - ofs] : 0;
        __syncthreads();
        part[tid] += t;
        __syncthreads();
    }
    int excl = part[tid] - v;
    start[tid] = excl; cur[tid] = excl;
    __syncthreads();

    for (int p = tid; p < cnt; p += 256) {
        u64 e = stag[p];
        int dl = ((unsigned)e) >> 24;
        int pos = atomicAdd(&cur[dl], 1);
        sorted[pos] = e;
    }
    __syncthreads();

    for (int p = tid; p < cnt; p += 256) bk[p] = sorted[p];

    int n = (bin << 8) + tid;
    if (n < N) {
        rstart[n] = bin * CAP + start[tid];
        rdeg[n] = hist[tid];
    }
}

// ---- phase 3: gather SpMM, one wave per node (lane = feature) ----
__global__ __launch_bounds__(256) void gather_kernel(
    const float* __restrict__ h, const u64* __restrict__ bucket,
    const int* __restrict__ rstart, const int* __restrict__ rdeg,
    float* __restrict__ agg, int N) {
    int lane = threadIdx.x & 63;
    int n = (blockIdx.x * 256 + threadIdx.x) >> 6;
    if (n >= N) return;
    int dg = rdeg[n];
    const u64* bk = bucket + rstart[n];
    float acc = 0.f;
    int t = 0;
    for (; t + 4 <= dg; t += 4) {
        u64 e0 = bk[t], e1 = bk[t + 1], e2 = bk[t + 2], e3 = bk[t + 3];
        float v0 = h[(size_t)(((unsigned)e0) & 0xFFFFFF) * DFEAT + lane];
        float v1 = h[(size_t)(((unsigned)e1) & 0xFFFFFF) * DFEAT + lane];
        float v2 = h[(size_t)(((unsigned)e2) & 0xFFFFFF) * DFEAT + lane];
        float v3 = h[(size_t)(((unsigned)e3) & 0xFFFFFF) * DFEAT + lane];
        acc += __int_as_float((int)(e0 >> 32)) * v0;
        acc += __int_as_float((int)(e1 >> 32)) * v1;
        acc += __int_as_float((int)(e2 >> 32)) * v2;
        acc += __int_as_float((int)(e3 >> 32)) * v3;
    }
    for (; t < dg; ++t) {
        u64 e = bk[t];
        acc += __int_as_float((int)(e >> 32)) *
               h[(size_t)(((unsigned)e) & 0xFFFFFF) * DFEAT + lane];
    }
    agg[(size_t)n * DFEAT + lane] = acc;
}

// ---- phase 4: epilogue, register-resident W (in-place on agg==out) ----
__global__ __launch_bounds__(256) void epilogue_kernel(
    const float* __restrict__ agg, const float* __restrict__ ifeat,
    const float* __restrict__ weight,   // [128][64] row-major
    const float* __restrict__ lamda_p, const float* __restrict__ alpha_p,
    const int* __restrict__ layer_p,
    float* __restrict__ out, int N, int total_waves) {
    int lane = threadIdx.x & 63;
    int wave = (blockIdx.x * 256 + threadIdx.x) >> 6;

    float wreg[128];
#pragma unroll
    for (int k = 0; k < 128; ++k) wreg[k] = weight[k * DFEAT + lane];

    float lam = lamda_p[0];
    float alpha = alpha_p[0];
    float theta = fminf(1.0f, logf(lam / (float)layer_p[0] + 1.0f));

    for (int r = wave; r < N; r += total_waves) {
        float hv = agg[(size_t)r * DFEAT + lane];
        float iv = ifeat[(size_t)r * DFEAT + lane];
        float acc = 0.f;
#pragma unroll
        for (int k = 0; k < 64; ++k)
            acc += lane_bcast(hv, k) * wreg[k];
#pragma unroll
        for (int k = 0; k < 64; ++k)
            acc += lane_bcast(iv, k) * wreg[64 + k];
        out[(size_t)r * DFEAT + lane] =
            theta * acc + (1.f - theta) * ((1.f - alpha) * hv + alpha * iv) + iv;
    }
}

extern "C" void kernel_launch(void* const* d_in, const int* in_sizes, int n_in,
                              void* d_out, int out_size, void* d_ws, size_t ws_size,
                              hipStream_t stream) {
    const float* h       = (const float*)d_in[0];
    const float* ifeat   = (const float*)d_in[1];
    const float* weight  = (const float*)d_in[2];
    const float* edge_w  = (const float*)d_in[3];
    const float* lamda_p = (const float*)d_in[4];
    const float* alpha_p = (const float*)d_in[5];
    const int*   e_src   = (const int*)d_in[6];
    const int*   e_dst   = (const int*)d_in[7];
    const int*   layer_p = (const int*)d_in[8];
    float* out = (float*)d_out;

    int N = in_sizes[0] / DFEAT;     // 100000
    int E = in_sizes[3];             // 1000000
    int nbins = (N + 255) >> 8;      // 391

    // ws: gcur[512] ints | bucket[nbins*CAP] u64 (~12.8 MB) | rstart | rdeg
    int* gcur = (int*)d_ws;
    u64* bucket = (u64*)((char*)d_ws + 4096);
    int* rstart = (int*)((char*)bucket + (size_t)nbins * CAP * sizeof(u64));
    int* rdeg = rstart + N;

    float* agg = out;   // epilogue is in-place per-row (verified R3)

    hipMemsetAsync(gcur, 0, NBINS * sizeof(int), stream);

    bin_fill_kernel<<<(E + CHUNK - 1) / CHUNK, TPB, 0, stream>>>(
        e_src, e_dst, edge_w, gcur, bucket, E);

    local_sort_kernel<<<nbins, 256, 0, stream>>>(bucket, gcur, rstart, rdeg, N);

    gather_kernel<<<(N + 3) / 4, 256, 0, stream>>>(
        h, bucket, rstart, rdeg, agg, N);

    int epi_blocks = 768;
    epilogue_kernel<<<epi_blocks, 256, 0, stream>>>(
        agg, ifeat, weight, lamda_p, alpha_p, layer_p, out, N, epi_blocks * 4);
}

// Round 5
// 205.227 us; speedup vs baseline: 3.0019x; 1.1369x over previous
//
#include <hip/hip_runtime.h>
#include <math.h>

// GraphConvolution (GCNII variant=True, residual=True), N=100k, E=1M, D=64.
//   agg[dst] += h[src] * edge_w
//   out = theta*([agg,i]@W) + (1-theta)*((1-alpha)*agg + alpha*i) + i
//
// R5: epilogue GEMM moved from readlane+fmac VALU broadcast (64us, VALU-bound)
// to mfma_f32_16x16x32_bf16 (memory-bound, ~77MB). Gather reads bf16 h
// (pre-converted, halves per-edge row traffic 256B -> 128B).

#define DFEAT 64
#define NBINS 512        // physical; logical bins = ceil(N/256) = 391
#define CAP   4096       // slots per bucket (mean 2558, sigma ~51)
#define CHUNK 4096       // edges per bin_fill block
#define TPB   512

typedef unsigned long long u64;
typedef __attribute__((ext_vector_type(8))) short bf16x8;
typedef __attribute__((ext_vector_type(4))) float f32x4;

__device__ inline unsigned short to_bf16(float f) {   // RNE
    unsigned u = __float_as_uint(f);
    u += 0x7FFF + ((u >> 16) & 1);
    return (unsigned short)(u >> 16);
}

// ---- phase 0: h (fp32) -> h16 (bf16) ----
__global__ __launch_bounds__(256) void cvt_h_kernel(
    const float* __restrict__ h, ushort* __restrict__ h16, int total4) {
    int i = blockIdx.x * 256 + threadIdx.x;
    if (i < total4) {
        float4 v = ((const float4*)h)[i];
        ushort4 o;
        o.x = to_bf16(v.x); o.y = to_bf16(v.y);
        o.z = to_bf16(v.z); o.w = to_bf16(v.w);
        ((ushort4*)h16)[i] = o;
    }
}

// ---- phase 1: bin edges by dst>>8 into fixed-capacity global buckets ----
// Entry: low32 = src | (dstLocal<<24), high32 = bits(w).
__global__ __launch_bounds__(512) void bin_fill_kernel(
    const int* __restrict__ e_src, const int* __restrict__ e_dst,
    const float* __restrict__ e_w, int* __restrict__ gcur,
    u64* __restrict__ bucket, int E) {
    __shared__ u64 staging[CHUNK];            // 32 KB
    __shared__ unsigned short binOf[CHUNK];   // 8 KB
    __shared__ int hist[NBINS], offs[NBINS], gbase[NBINS];
    __shared__ int cur[NBINS], part[TPB];

    int tid = threadIdx.x;
    int e0 = blockIdx.x * CHUNK;
    int cc = min(CHUNK, E - e0);

    hist[tid] = 0;
    __syncthreads();

    int d[8], s[8];
    float w[8];
#pragma unroll
    for (int j = 0; j < 8; ++j) {
        int e = e0 + j * TPB + tid;
        if (e < E) { d[j] = e_dst[e]; s[j] = e_src[e]; w[j] = e_w[e]; }
        else d[j] = -1;
    }
#pragma unroll
    for (int j = 0; j < 8; ++j)
        if (d[j] >= 0) atomicAdd(&hist[d[j] >> 8], 1);
    __syncthreads();

    int v = hist[tid];
    part[tid] = v;
    __syncthreads();
    for (int ofs = 1; ofs < TPB; ofs <<= 1) {
        int t = (tid >= ofs) ? part[tid - ofs] : 0;
        __syncthreads();
        part[tid] += t;
        __syncthreads();
    }
    int excl = part[tid] - v;
    offs[tid] = excl; cur[tid] = excl;
    __syncthreads();

#pragma unroll
    for (int j = 0; j < 8; ++j) {
        if (d[j] >= 0) {
            int bb = d[j] >> 8;
            int p = atomicAdd(&cur[bb], 1);
            unsigned lo = (unsigned)s[j] | ((unsigned)(d[j] & 255) << 24);
            staging[p] = ((u64)(unsigned)__float_as_int(w[j]) << 32) | lo;
            binOf[p] = (unsigned short)bb;
        }
    }
    __syncthreads();

    {
        int c = hist[tid];
        gbase[tid] = (c > 0) ? atomicAdd(&gcur[tid], c) : 0;
    }
    __syncthreads();

#pragma unroll
    for (int j = 0; j < 8; ++j) {
        int p = j * TPB + tid;
        if (p < cc) {
            int bb = binOf[p];
            bucket[(size_t)bb * CAP + gbase[bb] + (p - offs[bb])] = staging[p];
        }
    }
}

// ---- phase 2: per-bin counting sort by node -> exact CSR (in place) ----
__global__ __launch_bounds__(256) void local_sort_kernel(
    u64* __restrict__ bucket, const int* __restrict__ gcur,
    int* __restrict__ rstart, int* __restrict__ rdeg, int N) {
    __shared__ u64 stag[CAP];      // 32 KB
    __shared__ u64 sorted[CAP];    // 32 KB
    __shared__ int hist[256], start[256], cur[256], part[256];

    int bin = blockIdx.x, tid = threadIdx.x;
    int cnt = gcur[bin];
    u64* bk = bucket + (size_t)bin * CAP;

    hist[tid] = 0;
    __syncthreads();

    for (int p = tid; p < cnt; p += 256) {
        u64 e = bk[p];
        stag[p] = e;
        atomicAdd(&hist[((unsigned)e) >> 24], 1);
    }
    __syncthreads();

    int v = hist[tid];
    part[tid] = v;
    __syncthreads();
    for (int ofs = 1; ofs < 256; ofs <<= 1) {
        int t = (tid >= ofs) ? part[tid - ofs] : 0;
        __syncthreads();
        part[tid] += t;
        __syncthreads();
    }
    int excl = part[tid] - v;
    start[tid] = excl; cur[tid] = excl;
    __syncthreads();

    for (int p = tid; p < cnt; p += 256) {
        u64 e = stag[p];
        int pos = atomicAdd(&cur[((unsigned)e) >> 24], 1);
        sorted[pos] = e;
    }
    __syncthreads();

    for (int p = tid; p < cnt; p += 256) bk[p] = sorted[p];

    int n = (bin << 8) + tid;
    if (n < N) {
        rstart[n] = bin * CAP + start[tid];
        rdeg[n] = hist[tid];
    }
}

// ---- phase 3: gather SpMM, one wave per node (lane = feature), bf16 h ----
__global__ __launch_bounds__(256) void gather_kernel(
    const ushort* __restrict__ h16, const u64* __restrict__ bucket,
    const int* __restrict__ rstart, const int* __restrict__ rdeg,
    float* __restrict__ agg, int N) {
    int lane = threadIdx.x & 63;
    int n = (blockIdx.x * 256 + threadIdx.x) >> 6;
    if (n >= N) return;
    int dg = rdeg[n];
    const u64* bk = bucket + rstart[n];
    float acc = 0.f;
    int t = 0;
    for (; t + 4 <= dg; t += 4) {
        u64 e0 = bk[t], e1 = bk[t + 1], e2 = bk[t + 2], e3 = bk[t + 3];
        float v0 = __uint_as_float((unsigned)h16[(size_t)(((unsigned)e0) & 0xFFFFFF) * DFEAT + lane] << 16);
        float v1 = __uint_as_float((unsigned)h16[(size_t)(((unsigned)e1) & 0xFFFFFF) * DFEAT + lane] << 16);
        float v2 = __uint_as_float((unsigned)h16[(size_t)(((unsigned)e2) & 0xFFFFFF) * DFEAT + lane] << 16);
        float v3 = __uint_as_float((unsigned)h16[(size_t)(((unsigned)e3) & 0xFFFFFF) * DFEAT + lane] << 16);
        acc += __int_as_float((int)(e0 >> 32)) * v0;
        acc += __int_as_float((int)(e1 >> 32)) * v1;
        acc += __int_as_float((int)(e2 >> 32)) * v2;
        acc += __int_as_float((int)(e3 >> 32)) * v3;
    }
    for (; t < dg; ++t) {
        u64 e = bk[t];
        acc += __int_as_float((int)(e >> 32)) *
               __uint_as_float((unsigned)h16[(size_t)(((unsigned)e) & 0xFFFFFF) * DFEAT + lane] << 16);
    }
    agg[(size_t)n * DFEAT + lane] = acc;
}

// ---- phase 4: MFMA epilogue. One wave per 16-row tile, grid-stride. ----
// A = [agg | i] (N x 128, ->bf16), W = weight (128 x 64, ->bf16 frags).
// mfma_f32_16x16x32_bf16: A[m=lane&15][k=(lane>>4)*8+j], B[k][n=lane&15],
// C/D: col=lane&15, row=(lane>>4)*4+reg  (m89-verified).
// NOTE: agg aliases out (in-place per-tile) -> no __restrict__ on them.
__global__ __launch_bounds__(256) void epilogue_mfma_kernel(
    const float* agg, const float* __restrict__ ifeat,
    const float* __restrict__ weight,
    const float* __restrict__ lamda_p, const float* __restrict__ alpha_p,
    const int* __restrict__ layer_p,
    float* out, int N, int total_waves) {
    int lane = threadIdx.x & 63;
    int wave = (blockIdx.x * 256 + threadIdx.x) >> 6;
    int q = lane >> 4;        // quad 0..3
    int m = lane & 15;

    // W frags: bW[c][s][j] = bf16(W[s*32 + q*8 + j][c*16 + m])
    bf16x8 bW[4][4];
#pragma unroll
    for (int c = 0; c < 4; ++c)
#pragma unroll
        for (int s = 0; s < 4; ++s)
#pragma unroll
            for (int j = 0; j < 8; ++j)
                bW[c][s][j] = (short)to_bf16(weight[(s * 32 + q * 8 + j) * DFEAT + c * 16 + m]);

    float alf = alpha_p[0];
    float theta = fminf(1.0f, logf(lamda_p[0] / (float)layer_p[0] + 1.0f));

    int ntiles = (N + 15) >> 4;
    for (int t = wave; t < ntiles; t += total_waves) {
        int rbase = t << 4;
        int arow = min(rbase + m, N - 1);
        const float* ap = agg + (size_t)arow * DFEAT;
        const float* ip = ifeat + (size_t)arow * DFEAT;

        f32x4 acc[4] = {{0.f, 0.f, 0.f, 0.f}, {0.f, 0.f, 0.f, 0.f},
                        {0.f, 0.f, 0.f, 0.f}, {0.f, 0.f, 0.f, 0.f}};
#pragma unroll
        for (int s = 0; s < 4; ++s) {
            const float* p = ((s < 2) ? ap : ip) + ((s & 1) ? 32 : 0) + q * 8;
            float4 v0 = *(const float4*)p;
            float4 v1 = *(const float4*)(p + 4);
            bf16x8 fa;
            fa[0] = (short)to_bf16(v0.x); fa[1] = (short)to_bf16(v0.y);
            fa[2] = (short)to_bf16(v0.z); fa[3] = (short)to_bf16(v0.w);
            fa[4] = (short)to_bf16(v1.x); fa[5] = (short)to_bf16(v1.y);
            fa[6] = (short)to_bf16(v1.z); fa[7] = (short)to_bf16(v1.w);
#pragma unroll
            for (int c = 0; c < 4; ++c)
                acc[c] = __builtin_amdgcn_mfma_f32_16x16x32_bf16(fa, bW[c][s], acc[c], 0, 0, 0);
        }

        // mix + residual + store (C/D layout: row = rbase+q*4+r, col = c*16+m)
#pragma unroll
        for (int c = 0; c < 4; ++c) {
            int col = c * 16 + m;
#pragma unroll
            for (int r = 0; r < 4; ++r) {
                int row = rbase + q * 4 + r;
                if (row < N) {
                    size_t o = (size_t)row * DFEAT + col;
                    float av = agg[o], iv = ifeat[o];
                    out[o] = theta * acc[c][r] +
                             (1.f - theta) * ((1.f - alf) * av + alf * iv) + iv;
                }
            }
        }
    }
}

extern "C" void kernel_launch(void* const* d_in, const int* in_sizes, int n_in,
                              void* d_out, int out_size, void* d_ws, size_t ws_size,
                              hipStream_t stream) {
    const float* h       = (const float*)d_in[0];
    const float* ifeat   = (const float*)d_in[1];
    const float* weight  = (const float*)d_in[2];
    const float* edge_w  = (const float*)d_in[3];
    const float* lamda_p = (const float*)d_in[4];
    const float* alpha_p = (const float*)d_in[5];
    const int*   e_src   = (const int*)d_in[6];
    const int*   e_dst   = (const int*)d_in[7];
    const int*   layer_p = (const int*)d_in[8];
    float* out = (float*)d_out;

    int N = in_sizes[0] / DFEAT;     // 100000
    int E = in_sizes[3];             // 1000000
    int nbins = (N + 255) >> 8;      // 391

    // ws: gcur[512]+pad (4KB) | bucket (12.81MB) | rstart,rdeg (0.8MB) | h16 (12.8MB)
    int* gcur = (int*)d_ws;
    u64* bucket = (u64*)((char*)d_ws + 4096);
    int* rstart = (int*)((char*)bucket + (size_t)nbins * CAP * sizeof(u64));
    int* rdeg = rstart + N;
    ushort* h16 = (ushort*)(rdeg + N);

    float* agg = out;   // epilogue is in-place per 16-row tile

    hipMemsetAsync(gcur, 0, NBINS * sizeof(int), stream);

    int total4 = N * DFEAT / 4;
    cvt_h_kernel<<<(total4 + 255) / 256, 256, 0, stream>>>(h, h16, total4);

    bin_fill_kernel<<<(E + CHUNK - 1) / CHUNK, TPB, 0, stream>>>(
        e_src, e_dst, edge_w, gcur, bucket, E);

    local_sort_kernel<<<nbins, 256, 0, stream>>>(bucket, gcur, rstart, rdeg, N);

    gather_kernel<<<(N + 3) / 4, 256, 0, stream>>>(
        h16, bucket, rstart, rdeg, agg, N);

    // epilogue: 512 blocks * 4 waves = 2048 waves over 6250 tiles
    int epi_blocks = 512;
    epilogue_mfma_kernel<<<epi_blocks, 256, 0, stream>>>(
        agg, ifeat, weight, lamda_p, alpha_p, layer_p, out, N, epi_blocks * 4);
}

// Round 6
// 179.099 us; speedup vs baseline: 3.4398x; 1.1459x over previous
//
#include <hip/hip_runtime.h>
#include <math.h>

// GraphConvolution (GCNII variant=True, residual=True), N=100k, E=1M, D=64.
//   agg[dst] += h[src] * edge_w
//   out = theta*([agg,i]@W) + (1-theta)*((1-alpha)*agg + alpha*i) + i
//
// R6: local_sort + gather fused into one kernel (sort bin in LDS, gather from
// LDS). Gather restructured quad-parallel: each 16-lane quad owns one edge,
// lane loads 4 bf16 features (8B) -> one dwordx2 fetches 4 h-rows; 4-deep
// unroll = 16 rows in flight per wave; butterfly-reduce across quads.
// R5 gather was latency-bound (80 rows in flight/CU vs 133 needed).

#define DFEAT 64
#define NBINS 512        // physical; logical bins = ceil(N/256) = 391
#define CAP   4096       // slots per bucket (mean 2558, sigma ~51)
#define CHUNK 4096       // edges per bin_fill block
#define TPB   512

typedef unsigned long long u64;
typedef __attribute__((ext_vector_type(8))) short bf16x8;
typedef __attribute__((ext_vector_type(4))) float f32x4;

__device__ inline unsigned short to_bf16(float f) {   // RNE
    unsigned u = __float_as_uint(f);
    u += 0x7FFF + ((u >> 16) & 1);
    return (unsigned short)(u >> 16);
}
__device__ inline float bf_up(unsigned short s) {
    return __uint_as_float(((unsigned)s) << 16);
}

// ---- phase 0: h (fp32) -> h16 (bf16) ----
__global__ __launch_bounds__(256) void cvt_h_kernel(
    const float* __restrict__ h, ushort* __restrict__ h16, int total4) {
    int i = blockIdx.x * 256 + threadIdx.x;
    if (i < total4) {
        float4 v = ((const float4*)h)[i];
        ushort4 o;
        o.x = to_bf16(v.x); o.y = to_bf16(v.y);
        o.z = to_bf16(v.z); o.w = to_bf16(v.w);
        ((ushort4*)h16)[i] = o;
    }
}

// ---- phase 1: bin edges by dst>>8 into fixed-capacity global buckets ----
// Entry: low32 = src | (dstLocal<<24), high32 = bits(w).
__global__ __launch_bounds__(512) void bin_fill_kernel(
    const int* __restrict__ e_src, const int* __restrict__ e_dst,
    const float* __restrict__ e_w, int* __restrict__ gcur,
    u64* __restrict__ bucket, int E) {
    __shared__ u64 staging[CHUNK];            // 32 KB
    __shared__ unsigned short binOf[CHUNK];   // 8 KB
    __shared__ int hist[NBINS], offs[NBINS], gbase[NBINS];
    __shared__ int cur[NBINS], part[TPB];

    int tid = threadIdx.x;
    int e0 = blockIdx.x * CHUNK;
    int cc = min(CHUNK, E - e0);

    hist[tid] = 0;
    __syncthreads();

    int d[8], s[8];
    float w[8];
#pragma unroll
    for (int j = 0; j < 8; ++j) {
        int e = e0 + j * TPB + tid;
        if (e < E) { d[j] = e_dst[e]; s[j] = e_src[e]; w[j] = e_w[e]; }
        else d[j] = -1;
    }
#pragma unroll
    for (int j = 0; j < 8; ++j)
        if (d[j] >= 0) atomicAdd(&hist[d[j] >> 8], 1);
    __syncthreads();

    int v = hist[tid];
    part[tid] = v;
    __syncthreads();
    for (int ofs = 1; ofs < TPB; ofs <<= 1) {
        int t = (tid >= ofs) ? part[tid - ofs] : 0;
        __syncthreads();
        part[tid] += t;
        __syncthreads();
    }
    int excl = part[tid] - v;
    offs[tid] = excl; cur[tid] = excl;
    __syncthreads();

#pragma unroll
    for (int j = 0; j < 8; ++j) {
        if (d[j] >= 0) {
            int bb = d[j] >> 8;
            int p = atomicAdd(&cur[bb], 1);
            unsigned lo = (unsigned)s[j] | ((unsigned)(d[j] & 255) << 24);
            staging[p] = ((u64)(unsigned)__float_as_int(w[j]) << 32) | lo;
            binOf[p] = (unsigned short)bb;
        }
    }
    __syncthreads();

    {
        int c = hist[tid];
        gbase[tid] = (c > 0) ? atomicAdd(&gcur[tid], c) : 0;
    }
    __syncthreads();

#pragma unroll
    for (int j = 0; j < 8; ++j) {
        int p = j * TPB + tid;
        if (p < cc) {
            int bb = binOf[p];
            bucket[(size_t)bb * CAP + gbase[bb] + (p - offs[bb])] = staging[p];
        }
    }
}

// ---- phase 2: fused per-bin counting-sort (LDS) + quad-parallel gather ----
// 2 blocks per bin: both sort the bin into LDS; block parity picks which
// half of the 256 nodes it gathers. 512 thr, ~37 KB LDS -> 4 blocks/CU.
__global__ __launch_bounds__(512) void sort_gather_kernel(
    const ushort* __restrict__ h16, const u64* __restrict__ bucket,
    const int* __restrict__ gcur, float* __restrict__ agg, int N) {
    __shared__ u64 sorted[CAP];                     // 32 KB
    __shared__ int hist[256], start[256], cur[256], part[256];

    int tid = threadIdx.x;
    int bin = blockIdx.x >> 1;
    int half = blockIdx.x & 1;
    int cnt = gcur[bin];
    const u64* bk = bucket + (size_t)bin * CAP;

    if (tid < 256) hist[tid] = 0;
    __syncthreads();

    // pass 1: histogram by local node id (re-reads global; no LDS staging)
    for (int p = tid; p < cnt; p += 512)
        atomicAdd(&hist[((unsigned)bk[p]) >> 24], 1);
    __syncthreads();

    // exclusive scan of hist[256]
    int v = 0;
    if (tid < 256) { v = hist[tid]; part[tid] = v; }
    __syncthreads();
    for (int ofs = 1; ofs < 256; ofs <<= 1) {
        int t = 0;
        if (tid < 256 && tid >= ofs) t = part[tid - ofs];
        __syncthreads();
        if (tid < 256) part[tid] += t;
        __syncthreads();
    }
    if (tid < 256) { start[tid] = part[tid] - v; cur[tid] = part[tid] - v; }
    __syncthreads();

    // pass 2: permute into node-sorted LDS array
    for (int p = tid; p < cnt; p += 512) {
        u64 e = bk[p];
        int pos = atomicAdd(&cur[((unsigned)e) >> 24], 1);
        sorted[pos] = e;
    }
    __syncthreads();

    // gather: quad g owns edge t+g, lane covers features m*4..m*4+3
    int lane = tid & 63, wv = tid >> 6;   // 8 waves
    int g = lane >> 4, m = lane & 15;
    int base = bin << 8;
    int nn = min(256, N - base);

    for (int nl = half + 2 * wv; nl < nn; nl += 16) {
        int d = hist[nl];
        int b0 = start[nl];
        float a0 = 0.f, a1 = 0.f, a2 = 0.f, a3 = 0.f;
        for (int t0 = 0; t0 < d; t0 += 16) {
#pragma unroll
            for (int s = 0; s < 4; ++s) {
                int idx = t0 + s * 4 + g;
                u64 e = sorted[b0 + min(idx, d - 1)];
                float wt = (idx < d) ? __int_as_float((int)(e >> 32)) : 0.f;
                int src = ((unsigned)e) & 0xFFFFFF;
                ushort4 hv = *(const ushort4*)(h16 + (size_t)src * DFEAT + m * 4);
                a0 += wt * bf_up(hv.x);
                a1 += wt * bf_up(hv.y);
                a2 += wt * bf_up(hv.z);
                a3 += wt * bf_up(hv.w);
            }
        }
        // reduce across quads (xor 16, 32)
        a0 += __shfl_xor(a0, 16); a1 += __shfl_xor(a1, 16);
        a2 += __shfl_xor(a2, 16); a3 += __shfl_xor(a3, 16);
        a0 += __shfl_xor(a0, 32); a1 += __shfl_xor(a1, 32);
        a2 += __shfl_xor(a2, 32); a3 += __shfl_xor(a3, 32);
        if (g == 0) {
            float4 o; o.x = a0; o.y = a1; o.z = a2; o.w = a3;
            *(float4*)(agg + (size_t)(base + nl) * DFEAT + m * 4) = o;
        }
    }
}

// ---- phase 3: MFMA epilogue. One wave per 16-row tile, grid-stride. ----
// mfma_f32_16x16x32_bf16: A[m=lane&15][k=(lane>>4)*8+j], B[k][n=lane&15],
// C/D: col=lane&15, row=(lane>>4)*4+reg  (m89-verified).
// NOTE: agg aliases out (in-place per-tile) -> no __restrict__ on them.
__global__ __launch_bounds__(256) void epilogue_mfma_kernel(
    const float* agg, const float* __restrict__ ifeat,
    const float* __restrict__ weight,
    const float* __restrict__ lamda_p, const float* __restrict__ alpha_p,
    const int* __restrict__ layer_p,
    float* out, int N, int total_waves) {
    int lane = threadIdx.x & 63;
    int wave = (blockIdx.x * 256 + threadIdx.x) >> 6;
    int q = lane >> 4;
    int m = lane & 15;

    bf16x8 bW[4][4];
#pragma unroll
    for (int c = 0; c < 4; ++c)
#pragma unroll
        for (int s = 0; s < 4; ++s)
#pragma unroll
            for (int j = 0; j < 8; ++j)
                bW[c][s][j] = (short)to_bf16(weight[(s * 32 + q * 8 + j) * DFEAT + c * 16 + m]);

    float alf = alpha_p[0];
    float theta = fminf(1.0f, logf(lamda_p[0] / (float)layer_p[0] + 1.0f));

    int ntiles = (N + 15) >> 4;
    for (int t = wave; t < ntiles; t += total_waves) {
        int rbase = t << 4;
        int arow = min(rbase + m, N - 1);
        const float* ap = agg + (size_t)arow * DFEAT;
        const float* ip = ifeat + (size_t)arow * DFEAT;

        f32x4 acc[4] = {{0.f, 0.f, 0.f, 0.f}, {0.f, 0.f, 0.f, 0.f},
                        {0.f, 0.f, 0.f, 0.f}, {0.f, 0.f, 0.f, 0.f}};
#pragma unroll
        for (int s = 0; s < 4; ++s) {
            const float* p = ((s < 2) ? ap : ip) + ((s & 1) ? 32 : 0) + q * 8;
            float4 v0 = *(const float4*)p;
            float4 v1 = *(const float4*)(p + 4);
            bf16x8 fa;
            fa[0] = (short)to_bf16(v0.x); fa[1] = (short)to_bf16(v0.y);
            fa[2] = (short)to_bf16(v0.z); fa[3] = (short)to_bf16(v0.w);
            fa[4] = (short)to_bf16(v1.x); fa[5] = (short)to_bf16(v1.y);
            fa[6] = (short)to_bf16(v1.z); fa[7] = (short)to_bf16(v1.w);
#pragma unroll
            for (int c = 0; c < 4; ++c)
                acc[c] = __builtin_amdgcn_mfma_f32_16x16x32_bf16(fa, bW[c][s], acc[c], 0, 0, 0);
        }

#pragma unroll
        for (int c = 0; c < 4; ++c) {
            int col = c * 16 + m;
#pragma unroll
            for (int r = 0; r < 4; ++r) {
                int row = rbase + q * 4 + r;
                if (row < N) {
                    size_t o = (size_t)row * DFEAT + col;
                    float av = agg[o], iv = ifeat[o];
                    out[o] = theta * acc[c][r] +
                             (1.f - theta) * ((1.f - alf) * av + alf * iv) + iv;
                }
            }
        }
    }
}

extern "C" void kernel_launch(void* const* d_in, const int* in_sizes, int n_in,
                              void* d_out, int out_size, void* d_ws, size_t ws_size,
                              hipStream_t stream) {
    const float* h       = (const float*)d_in[0];
    const float* ifeat   = (const float*)d_in[1];
    const float* weight  = (const float*)d_in[2];
    const float* edge_w  = (const float*)d_in[3];
    const float* lamda_p = (const float*)d_in[4];
    const float* alpha_p = (const float*)d_in[5];
    const int*   e_src   = (const int*)d_in[6];
    const int*   e_dst   = (const int*)d_in[7];
    const int*   layer_p = (const int*)d_in[8];
    float* out = (float*)d_out;

    int N = in_sizes[0] / DFEAT;     // 100000
    int E = in_sizes[3];             // 1000000
    int nbins = (N + 255) >> 8;      // 391

    // ws: gcur[512]+pad (4KB) | bucket (12.81MB) | h16 (12.8MB)
    int* gcur = (int*)d_ws;
    u64* bucket = (u64*)((char*)d_ws + 4096);
    ushort* h16 = (ushort*)((char*)bucket + (size_t)nbins * CAP * sizeof(u64));

    float* agg = out;   // epilogue is in-place per 16-row tile

    hipMemsetAsync(gcur, 0, NBINS * sizeof(int), stream);

    int total4 = N * DFEAT / 4;
    cvt_h_kernel<<<(total4 + 255) / 256, 256, 0, stream>>>(h, h16, total4);

    bin_fill_kernel<<<(E + CHUNK - 1) / CHUNK, TPB, 0, stream>>>(
        e_src, e_dst, edge_w, gcur, bucket, E);

    // fused sort+gather: 2 blocks per bin (half the nodes each)
    sort_gather_kernel<<<nbins * 2, 512, 0, stream>>>(h16, bucket, gcur, agg, N);

    int epi_blocks = 512;
    epilogue_mfma_kernel<<<epi_blocks, 256, 0, stream>>>(
        agg, ifeat, weight, lamda_p, alpha_p, layer_p, out, N, epi_blocks * 4);
}